// Round 10
// baseline (412.006 us; speedup 1.0000x reference)
//
#include <hip/hip_runtime.h>

#define N_NODES   100000
#define N_EDGES   3200000
#define F_INP     128
#define HID       64
#define N_GRAPHS  512
#define N_CLASSES 2
#define NB        782                      // ceil(N/128) buckets of 128 target nodes
#define SCAT_BLOCKS 256
#define CHUNK     (N_EDGES / SCAT_BLOCKS)  // 12500, exact

// bf16 helpers: RTN encode; decode low/high halves of a packed u32
__device__ __forceinline__ unsigned short f2bf(float f) {
    unsigned int u = __float_as_uint(f);
    return (unsigned short)((u + 0x7FFFu + ((u >> 16) & 1u)) >> 16);
}
__device__ __forceinline__ float bf_lo(unsigned int u) { return __uint_as_float(u << 16); }
__device__ __forceinline__ float bf_hi(unsigned int u) { return __uint_as_float(u & 0xFFFF0000u); }

// ---------- pass 1: per-block bucket histogram -> bh + global bcnt ----------
__global__ __launch_bounds__(256) void hist_kernel(const int* __restrict__ ei,
                                                   int* __restrict__ bcnt,
                                                   int* __restrict__ bh) {
    __shared__ int hist[NB];
    for (int i = threadIdx.x; i < NB; i += 256) hist[i] = 0;
    __syncthreads();
    const int e0 = blockIdx.x * CHUNK, e1 = e0 + CHUNK;
    for (int e = e0 + threadIdx.x; e < e1; e += 256)
        atomicAdd(&hist[ei[N_EDGES + e] >> 7], 1);
    __syncthreads();
    for (int i = threadIdx.x; i < NB; i += 256) {
        int v = hist[i];
        bh[(size_t)blockIdx.x * NB + i] = v;
        if (v) atomicAdd(&bcnt[i], v);
    }
}

// ---------- pass 2: exclusive scan over 782 buckets (one block) ----------
__global__ __launch_bounds__(1024) void scan_kernel(const int* __restrict__ bcnt,
                                                    int* __restrict__ boff) {
    __shared__ int s[1024];
    const int tid = threadIdx.x;
    const int v = (tid < NB) ? bcnt[tid] : 0;
    s[tid] = v;
    __syncthreads();
    for (int d = 1; d < 1024; d <<= 1) {
        int t = (tid >= d) ? s[tid - d] : 0;
        __syncthreads();
        s[tid] += t;
        __syncthreads();
    }
    if (tid <= NB) boff[tid] = s[tid] - v;   // exclusive; tid==NB -> N_EDGES
}

// ---------- pass 2b: per-(block,bucket) bases, coalesced: thread = bucket ----------
__global__ __launch_bounds__(64) void bbase_kernel(int* __restrict__ bh,
                                                   const int* __restrict__ boff) {
    const int b = blockIdx.x * 64 + threadIdx.x;
    if (b >= NB) return;
    int base = boff[b];
    for (int i = 0; i < SCAT_BLOCKS; i += 8) {
        int v[8];
#pragma unroll
        for (int j = 0; j < 8; ++j) v[j] = bh[(size_t)(i + j) * NB + b];
#pragma unroll
        for (int j = 0; j < 8; ++j) { bh[(size_t)(i + j) * NB + b] = base; base += v[j]; }
    }
}

// ---------- pass 3: single-pass localized scatter using precomputed bases ----------
// pairs[e] = r | ((c & 127) << 17);  r < 2^17
__global__ __launch_bounds__(256) void scatter_kernel(const int* __restrict__ ei,
                                                      const int* __restrict__ bh,
                                                      int* __restrict__ pairs) {
    __shared__ int lbase[NB];
    __shared__ int lcur[NB];
    for (int i = threadIdx.x; i < NB; i += 256) {
        lbase[i] = bh[(size_t)blockIdx.x * NB + i];
        lcur[i] = 0;
    }
    __syncthreads();
    const int e0 = blockIdx.x * CHUNK, e1 = e0 + CHUNK;
    for (int e = e0 + threadIdx.x; e < e1; e += 256) {
        int c = ei[N_EDGES + e];
        int r = ei[e];
        int b = c >> 7;
        int off = atomicAdd(&lcur[b], 1);
        pairs[lbase[b] + off] = r | ((c & 127) << 17);
    }
}

// ---------- pass 4: per-bucket CSR build (coalesced adj writes) + offs + dis ----------
__global__ __launch_bounds__(256) void csr_kernel(const int* __restrict__ pairs,
                                                  const int* __restrict__ boff,
                                                  int* __restrict__ adj,
                                                  int* __restrict__ offs,
                                                  float* __restrict__ dis) {
    __shared__ int cnt[128];
    __shared__ int sc[128];
    __shared__ int base[128];
    __shared__ int cur[128];
    const int tid = threadIdx.x;
    const int b = blockIdx.x;
    const int beg = boff[b], end = boff[b + 1];
    if (tid < 128) { cnt[tid] = 0; cur[tid] = 0; }
    __syncthreads();
    for (int e = beg + tid; e < end; e += 256)
        atomicAdd(&cnt[pairs[e] >> 17], 1);
    __syncthreads();
    if (tid < 128) sc[tid] = cnt[tid];
    __syncthreads();
    for (int d = 1; d < 128; d <<= 1) {
        int t = (tid >= d && tid < 128) ? sc[tid - d] : 0;
        __syncthreads();
        if (tid < 128) sc[tid] += t;
        __syncthreads();
    }
    if (tid < 128) base[tid] = beg + sc[tid] - cnt[tid];   // exclusive + bucket base
    __syncthreads();
    for (int e = beg + tid; e < end; e += 256) {
        int v = pairs[e];
        int lc = v >> 17;
        int o = atomicAdd(&cur[lc], 1);
        adj[base[lc] + o] = v & 131071;
    }
    const int n = (b << 7) + tid;
    if (tid < 128 && n < N_NODES) {
        offs[n] = base[tid];
        dis[n] = rsqrtf((float)cnt[tid] + 1.0f);           // +1 = self-loop
    }
    if (b == 0 && tid == 0) offs[N_NODES] = N_EDGES;
}

// ---------- mm1: p = bf16(dis * (x @ W1)), 32-row LDS tile, padded (no bank conflicts) ----------
#define MM1_ROWS 32
#define XS_LD    132                       // 128 + 4 pad floats -> bank shift 4/row
__global__ __launch_bounds__(256) void mm1_kernel(const float* __restrict__ x,
                                                  const float* __restrict__ W1,
                                                  const float* __restrict__ dis,
                                                  unsigned short* __restrict__ p) {
    __shared__ float xs[MM1_ROWS * XS_LD]; // 16.9 KB
    __shared__ float ws[F_INP * HID];      // 32 KB
    for (int i = threadIdx.x; i < F_INP * HID / 4; i += 256)
        ((float4*)ws)[i] = ((const float4*)W1)[i];
    const int row_base = blockIdx.x * MM1_ROWS;
    for (int i = threadIdx.x; i < MM1_ROWS * (F_INP / 4); i += 256) {
        int r = i >> 5, c4 = i & 31;
        int gr = row_base + r;
        float4 v = make_float4(0.f, 0.f, 0.f, 0.f);
        if (gr < N_NODES) v = *(const float4*)(x + (size_t)gr * F_INP + c4 * 4);
        *(float4*)(xs + r * XS_LD + c4 * 4) = v;
    }
    __syncthreads();
    const int tx = threadIdx.x & 15;
    const int ty = threadIdx.x >> 4;
    float acc[2][4] = {};
#pragma unroll 4
    for (int k = 0; k < F_INP; k += 4) {
        float4 a0 = *(const float4*)(xs + ty * XS_LD + k);
        float4 a1 = *(const float4*)(xs + (ty + 16) * XS_LD + k);
        float4 w0 = *(const float4*)(ws + (k + 0) * HID + tx * 4);
        float4 w1 = *(const float4*)(ws + (k + 1) * HID + tx * 4);
        float4 w2 = *(const float4*)(ws + (k + 2) * HID + tx * 4);
        float4 w3 = *(const float4*)(ws + (k + 3) * HID + tx * 4);
        acc[0][0] += a0.x * w0.x + a0.y * w1.x + a0.z * w2.x + a0.w * w3.x;
        acc[0][1] += a0.x * w0.y + a0.y * w1.y + a0.z * w2.y + a0.w * w3.y;
        acc[0][2] += a0.x * w0.z + a0.y * w1.z + a0.z * w2.z + a0.w * w3.z;
        acc[0][3] += a0.x * w0.w + a0.y * w1.w + a0.z * w2.w + a0.w * w3.w;
        acc[1][0] += a1.x * w0.x + a1.y * w1.x + a1.z * w2.x + a1.w * w3.x;
        acc[1][1] += a1.x * w0.y + a1.y * w1.y + a1.z * w2.y + a1.w * w3.y;
        acc[1][2] += a1.x * w0.z + a1.y * w1.z + a1.z * w2.z + a1.w * w3.z;
        acc[1][3] += a1.x * w0.w + a1.y * w1.w + a1.z * w2.w + a1.w * w3.w;
    }
#pragma unroll
    for (int i = 0; i < 2; ++i) {
        int rr = row_base + ty + 16 * i;
        if (rr < N_NODES) {
            float d = dis[rr];
            ushort4 o;
            o.x = f2bf(d * acc[i][0]);
            o.y = f2bf(d * acc[i][1]);
            o.z = f2bf(d * acc[i][2]);
            o.w = f2bf(d * acc[i][3]);
            *(ushort4*)(p + (size_t)rr * HID + tx * 4) = o;
        }
    }
}

// ---------- mm2: p = bf16(dis * (h @ W2)), 64-row bf16 tile, padded ----------
#define HS_LD 72                            // 64 + 8 pad bf16 -> 144 B/row, bank shift 4
__global__ __launch_bounds__(256) void mm2_kernel(const unsigned short* __restrict__ hb,
                                                  const float* __restrict__ W2,
                                                  const float* __restrict__ dis,
                                                  unsigned short* __restrict__ p) {
    __shared__ unsigned short hs[64 * HS_LD];  // 9.2 KB
    __shared__ float ws[HID * HID];            // 16 KB
    for (int i = threadIdx.x; i < HID * HID / 4; i += 256)
        ((float4*)ws)[i] = ((const float4*)W2)[i];
    const int row_base = blockIdx.x * 64;
    for (int i = threadIdx.x; i < 64 * (HID / 8); i += 256) {
        int r = i >> 3, c8 = i & 7;
        int gr = row_base + r;
        uint4 v = make_uint4(0u, 0u, 0u, 0u);
        if (gr < N_NODES) v = *(const uint4*)(hb + (size_t)gr * HID + c8 * 8);
        *(uint4*)(hs + r * HS_LD + c8 * 8) = v;
    }
    __syncthreads();
    const int tx = threadIdx.x & 15;
    const int ty = threadIdx.x >> 4;
    float acc[4][4] = {};
#pragma unroll 2
    for (int k = 0; k < HID; k += 8) {
        uint4 a[4];
#pragma unroll
        for (int i = 0; i < 4; ++i)
            a[i] = *(const uint4*)(hs + (ty + 16 * i) * HS_LD + k);
        float4 w[8];
#pragma unroll
        for (int m = 0; m < 8; ++m)
            w[m] = *(const float4*)(ws + (k + m) * HID + tx * 4);
#pragma unroll
        for (int i = 0; i < 4; ++i) {
            float h0 = bf_lo(a[i].x), h1 = bf_hi(a[i].x);
            float h2 = bf_lo(a[i].y), h3 = bf_hi(a[i].y);
            float h4 = bf_lo(a[i].z), h5 = bf_hi(a[i].z);
            float h6 = bf_lo(a[i].w), h7 = bf_hi(a[i].w);
            acc[i][0] += h0 * w[0].x + h1 * w[1].x + h2 * w[2].x + h3 * w[3].x
                       + h4 * w[4].x + h5 * w[5].x + h6 * w[6].x + h7 * w[7].x;
            acc[i][1] += h0 * w[0].y + h1 * w[1].y + h2 * w[2].y + h3 * w[3].y
                       + h4 * w[4].y + h5 * w[5].y + h6 * w[6].y + h7 * w[7].y;
            acc[i][2] += h0 * w[0].z + h1 * w[1].z + h2 * w[2].z + h3 * w[3].z
                       + h4 * w[4].z + h5 * w[5].z + h6 * w[6].z + h7 * w[7].z;
            acc[i][3] += h0 * w[0].w + h1 * w[1].w + h2 * w[2].w + h3 * w[3].w
                       + h4 * w[4].w + h5 * w[5].w + h6 * w[6].w + h7 * w[7].w;
        }
    }
#pragma unroll
    for (int i = 0; i < 4; ++i) {
        int rr = row_base + ty + 16 * i;
        if (rr < N_NODES) {
            float d = dis[rr];
            ushort4 o;
            o.x = f2bf(d * acc[i][0]);
            o.y = f2bf(d * acc[i][1]);
            o.z = f2bf(d * acc[i][2]);
            o.w = f2bf(d * acc[i][3]);
            *(ushort4*)(p + (size_t)rr * HID + tx * 4) = o;
        }
    }
}

// ---------- high-MLP gather core: 8 rows per dwordx4, 64 edges/iter (8 loads in flight) ----------
// lane L: q = L>>3 (row slot), g = L&7 (feature octet, feats 8g..8g+7)
__device__ __forceinline__ float gather_node(const unsigned short* __restrict__ pg,
                                             const int* __restrict__ adj,
                                             int c, int beg, int end, int q) {
    float acc[8];
    {   // self-loop row, counted once via q==0 lanes
        uint4 s = *(const uint4*)(pg + (size_t)c * HID);
        float sm = (q == 0) ? 1.f : 0.f;
        acc[0] = sm * bf_lo(s.x); acc[1] = sm * bf_hi(s.x);
        acc[2] = sm * bf_lo(s.y); acc[3] = sm * bf_hi(s.y);
        acc[4] = sm * bf_lo(s.z); acc[5] = sm * bf_hi(s.z);
        acc[6] = sm * bf_lo(s.w); acc[7] = sm * bf_hi(s.w);
    }
    int e = beg;
    for (; e + 64 <= end; e += 64) {            // 8 row-loads in flight
        uint4 v[8];
#pragma unroll
        for (int j = 0; j < 8; ++j) {
            int r = adj[e + 8 * j + q];
            v[j] = *(const uint4*)(pg + (size_t)r * HID);
        }
#pragma unroll
        for (int j = 0; j < 8; ++j) {
            acc[0] += bf_lo(v[j].x); acc[1] += bf_hi(v[j].x);
            acc[2] += bf_lo(v[j].y); acc[3] += bf_hi(v[j].y);
            acc[4] += bf_lo(v[j].z); acc[5] += bf_hi(v[j].z);
            acc[6] += bf_lo(v[j].w); acc[7] += bf_hi(v[j].w);
        }
    }
    for (; e + 16 <= end; e += 16) {
        int r0 = adj[e + q];
        int r1 = adj[e + 8 + q];
        uint4 v0 = *(const uint4*)(pg + (size_t)r0 * HID);
        uint4 v1 = *(const uint4*)(pg + (size_t)r1 * HID);
        acc[0] += bf_lo(v0.x) + bf_lo(v1.x); acc[1] += bf_hi(v0.x) + bf_hi(v1.x);
        acc[2] += bf_lo(v0.y) + bf_lo(v1.y); acc[3] += bf_hi(v0.y) + bf_hi(v1.y);
        acc[4] += bf_lo(v0.z) + bf_lo(v1.z); acc[5] += bf_hi(v0.z) + bf_hi(v1.z);
        acc[6] += bf_lo(v0.w) + bf_lo(v1.w); acc[7] += bf_hi(v0.w) + bf_hi(v1.w);
    }
    for (; e < end; e += 8) {                   // masked tail
        int idx = e + q;
        int r = adj[min(idx, end - 1)];
        float m = (idx < end) ? 1.f : 0.f;
        uint4 v = *(const uint4*)(pg + (size_t)r * HID);
        acc[0] = fmaf(m, bf_lo(v.x), acc[0]); acc[1] = fmaf(m, bf_hi(v.x), acc[1]);
        acc[2] = fmaf(m, bf_lo(v.y), acc[2]); acc[3] = fmaf(m, bf_hi(v.y), acc[3]);
        acc[4] = fmaf(m, bf_lo(v.z), acc[4]); acc[5] = fmaf(m, bf_hi(v.z), acc[5]);
        acc[6] = fmaf(m, bf_lo(v.w), acc[6]); acc[7] = fmaf(m, bf_hi(v.w), acc[7]);
    }
    // select-tree reduction over q bits (lane ends with feature 8g+q)
    const bool q0 = (q & 1) != 0, q1 = (q & 2) != 0, q2 = (q & 4) != 0;
    float b0 = (q0 ? acc[1] : acc[0]) + __shfl_xor(q0 ? acc[0] : acc[1], 8, 64);
    float b1 = (q0 ? acc[3] : acc[2]) + __shfl_xor(q0 ? acc[2] : acc[3], 8, 64);
    float b2 = (q0 ? acc[5] : acc[4]) + __shfl_xor(q0 ? acc[4] : acc[5], 8, 64);
    float b3 = (q0 ? acc[7] : acc[6]) + __shfl_xor(q0 ? acc[6] : acc[7], 8, 64);
    float c0 = (q1 ? b1 : b0) + __shfl_xor(q1 ? b0 : b1, 16, 64);
    float c1 = (q1 ? b3 : b2) + __shfl_xor(q1 ? b2 : b3, 16, 64);
    return (q2 ? c1 : c0) + __shfl_xor(q2 ? c0 : c1, 32, 64);
}

// ---------- gather1: hb = bf16(relu(dis[c]*(p[c]+sum p[r]) + b1)), contiguous chunks ----------
__global__ __launch_bounds__(256) void gather1_kernel(const unsigned short* __restrict__ p,
                                                      const int* __restrict__ adj,
                                                      const int* __restrict__ offs,
                                                      const float* __restrict__ dis,
                                                      const float* __restrict__ b1,
                                                      unsigned short* __restrict__ hb) {
    const int lane = threadIdx.x & 63;
    const int q = lane >> 3, g = lane & 7;
    const unsigned short* pg = p + g * 8;
    const int gwave = (blockIdx.x * blockDim.x + threadIdx.x) >> 6;
    const int nwaves = (gridDim.x * blockDim.x) >> 6;
    const int per = (N_NODES + nwaves - 1) / nwaves;
    const int c0 = gwave * per;
    const int c1 = min(N_NODES, c0 + per);
    const float bj = b1[g * 8 + q];
    for (int c = c0; c < c1; ++c) {
        const int beg = offs[c], end = offs[c + 1];
        float val = gather_node(pg, adj, c, beg, end, q);
        hb[(size_t)c * HID + g * 8 + q] = f2bf(fmaxf(dis[c] * val + bj, 0.f));
    }
}

// ---------- gather2 + mean-pool numerator (run-length atomics over sorted batch) ----------
__global__ __launch_bounds__(256) void gather2_kernel(const unsigned short* __restrict__ p,
                                                      const int* __restrict__ adj,
                                                      const int* __restrict__ offs,
                                                      const float* __restrict__ dis,
                                                      const float* __restrict__ b2,
                                                      const int* __restrict__ batch,
                                                      float* __restrict__ sums) {
    const int lane = threadIdx.x & 63;
    const int q = lane >> 3, g = lane & 7;
    const unsigned short* pg = p + g * 8;
    const int gwave = (blockIdx.x * blockDim.x + threadIdx.x) >> 6;
    const int nwaves = (gridDim.x * blockDim.x) >> 6;
    const int per = (N_NODES + nwaves - 1) / nwaves;
    const int c0 = gwave * per;
    const int c1 = min(N_NODES, c0 + per);
    const float bj = b2[g * 8 + q];
    const int feat = g * 8 + q;
    float part = 0.f;
    int gc = -1;
    for (int c = c0; c < c1; ++c) {
        const int beg = offs[c], end = offs[c + 1];
        float val = gather_node(pg, adj, c, beg, end, q);
        float v = fmaxf(dis[c] * val + bj, 0.f);
        int gid = batch[c];                       // wave-uniform
        if (gid != gc) {
            if (gc >= 0) atomicAdd(&sums[(size_t)gc * HID + feat], part);
            part = 0.f;
            gc = gid;
        }
        part += v;
    }
    if (gc >= 0) atomicAdd(&sums[(size_t)gc * HID + feat], part);
}

// ---------- final FC (counts fused via binary search on sorted batch) ----------
__global__ void fc_kernel(const float* __restrict__ sums, const int* __restrict__ batch,
                          const float* __restrict__ Wfc, const float* __restrict__ bfc,
                          float* __restrict__ out) {
    const int g = blockIdx.x;
    const int j = threadIdx.x;
    int lo = 0, hi = N_NODES;
    while (lo < hi) { int m = (lo + hi) >> 1; if (batch[m] < g) lo = m + 1; else hi = m; }
    const int l0 = lo;
    lo = 0; hi = N_NODES;
    while (lo < hi) { int m = (lo + hi) >> 1; if (batch[m] < g + 1) lo = m + 1; else hi = m; }
    float cnt = fmaxf((float)(lo - l0), 1.0f);
    float pj = sums[(size_t)g * HID + j] / cnt;
    float a0 = pj * Wfc[j * N_CLASSES + 0];
    float a1 = pj * Wfc[j * N_CLASSES + 1];
    for (int off = 32; off > 0; off >>= 1) {
        a0 += __shfl_down(a0, off, 64);
        a1 += __shfl_down(a1, off, 64);
    }
    if (j == 0) {
        out[g * N_CLASSES + 0] = a0 + bfc[0];
        out[g * N_CLASSES + 1] = a1 + bfc[1];
    }
}

extern "C" void kernel_launch(void* const* d_in, const int* in_sizes, int n_in,
                              void* d_out, int out_size, void* d_ws, size_t ws_size,
                              hipStream_t stream) {
    const float* x     = (const float*)d_in[0];
    const int*   ei    = (const int*)d_in[1];   // [2,E]: row=ei[0:E], col=ei[E:2E]
    const int*   batch = (const int*)d_in[2];
    const float* W1    = (const float*)d_in[3];
    const float* b1    = (const float*)d_in[4];
    const float* W2    = (const float*)d_in[5];
    const float* b2    = (const float*)d_in[6];
    const float* Wfc   = (const float*)d_in[7];
    const float* bfc   = (const float*)d_in[8];
    float* out = (float*)d_out;

    char* ws = (char*)d_ws;
    size_t off = 0;
    auto alloc = [&](size_t bytes) -> void* {
        void* pp = ws + off;
        off += (bytes + 255) & ~(size_t)255;
        return pp;
    };
    int*   bcnt   = (int*)alloc((size_t)NB * 4);
    int*   boff   = (int*)alloc((size_t)(NB + 1) * 4);
    int*   bh     = (int*)alloc((size_t)SCAT_BLOCKS * NB * 4);   // per-block hist -> bases
    float* dis    = (float*)alloc((size_t)N_NODES * 4);
    int*   pairs  = (int*)alloc((size_t)N_EDGES * 4);
    int*   adj    = (int*)alloc((size_t)N_EDGES * 4);
    int*   offs   = (int*)alloc((size_t)(N_NODES + 1) * 4);
    unsigned short* p  = (unsigned short*)alloc((size_t)N_NODES * HID * 2);
    unsigned short* hb = (unsigned short*)alloc((size_t)N_NODES * HID * 2);
    float* sums   = (float*)alloc((size_t)N_GRAPHS * HID * 4);

    hipMemsetAsync(bcnt, 0, (size_t)NB * 4, stream);
    hipMemsetAsync(sums, 0, (size_t)N_GRAPHS * HID * 4, stream);

    hist_kernel<<<SCAT_BLOCKS, 256, 0, stream>>>(ei, bcnt, bh);
    scan_kernel<<<1, 1024, 0, stream>>>(bcnt, boff);
    bbase_kernel<<<(NB + 63) / 64, 64, 0, stream>>>(bh, boff);
    scatter_kernel<<<SCAT_BLOCKS, 256, 0, stream>>>(ei, bh, pairs);
    csr_kernel<<<NB, 256, 0, stream>>>(pairs, boff, adj, offs, dis);
    mm1_kernel<<<(N_NODES + MM1_ROWS - 1) / MM1_ROWS, 256, 0, stream>>>(x, W1, dis, p);
    gather1_kernel<<<2048, 256, 0, stream>>>(p, adj, offs, dis, b1, hb);
    mm2_kernel<<<(N_NODES + 63) / 64, 256, 0, stream>>>(hb, W2, dis, p);
    gather2_kernel<<<2048, 256, 0, stream>>>(p, adj, offs, dis, b2, batch, sums);
    fc_kernel<<<N_GRAPHS, 64, 0, stream>>>(sums, batch, Wfc, bfc, out);
}

// Round 11
// 402.017 us; speedup vs baseline: 1.0248x; 1.0248x over previous
//
#include <hip/hip_runtime.h>

#define N_NODES   100000
#define N_EDGES   3200000
#define F_INP     128
#define HID       64
#define N_GRAPHS  512
#define N_CLASSES 2
#define NB        782                      // ceil(N/128) buckets of 128 target nodes
#define SCAT_BLOCKS 256
#define CHUNK     (N_EDGES / SCAT_BLOCKS)  // 12500, exact

// bf16 helpers: RTN encode; decode low/high halves of a packed u32
__device__ __forceinline__ unsigned short f2bf(float f) {
    unsigned int u = __float_as_uint(f);
    return (unsigned short)((u + 0x7FFFu + ((u >> 16) & 1u)) >> 16);
}
__device__ __forceinline__ float bf_lo(unsigned int u) { return __uint_as_float(u << 16); }
__device__ __forceinline__ float bf_hi(unsigned int u) { return __uint_as_float(u & 0xFFFF0000u); }

// ---------- pass 1: per-block bucket histogram -> bh + global bcnt ----------
__global__ __launch_bounds__(256) void hist_kernel(const int* __restrict__ ei,
                                                   int* __restrict__ bcnt,
                                                   int* __restrict__ bh) {
    __shared__ int hist[NB];
    for (int i = threadIdx.x; i < NB; i += 256) hist[i] = 0;
    __syncthreads();
    const int e0 = blockIdx.x * CHUNK, e1 = e0 + CHUNK;
    for (int e = e0 + threadIdx.x; e < e1; e += 256)
        atomicAdd(&hist[ei[N_EDGES + e] >> 7], 1);
    __syncthreads();
    for (int i = threadIdx.x; i < NB; i += 256) {
        int v = hist[i];
        bh[(size_t)blockIdx.x * NB + i] = v;
        if (v) atomicAdd(&bcnt[i], v);
    }
}

// ---------- pass 2: exclusive scan over 782 buckets (one block) ----------
__global__ __launch_bounds__(1024) void scan_kernel(const int* __restrict__ bcnt,
                                                    int* __restrict__ boff) {
    __shared__ int s[1024];
    const int tid = threadIdx.x;
    const int v = (tid < NB) ? bcnt[tid] : 0;
    s[tid] = v;
    __syncthreads();
    for (int d = 1; d < 1024; d <<= 1) {
        int t = (tid >= d) ? s[tid - d] : 0;
        __syncthreads();
        s[tid] += t;
        __syncthreads();
    }
    if (tid <= NB) boff[tid] = s[tid] - v;   // exclusive; tid==NB -> N_EDGES
}

// ---------- pass 2b: per-(block,bucket) bases, coalesced: thread = bucket ----------
__global__ __launch_bounds__(64) void bbase_kernel(int* __restrict__ bh,
                                                   const int* __restrict__ boff) {
    const int b = blockIdx.x * 64 + threadIdx.x;
    if (b >= NB) return;
    int base = boff[b];
    for (int i = 0; i < SCAT_BLOCKS; i += 8) {
        int v[8];
#pragma unroll
        for (int j = 0; j < 8; ++j) v[j] = bh[(size_t)(i + j) * NB + b];
#pragma unroll
        for (int j = 0; j < 8; ++j) { bh[(size_t)(i + j) * NB + b] = base; base += v[j]; }
    }
}

// ---------- pass 3: single-pass localized scatter using precomputed bases ----------
// pairs[e] = r | ((c & 127) << 17);  r < 2^17
__global__ __launch_bounds__(256) void scatter_kernel(const int* __restrict__ ei,
                                                      const int* __restrict__ bh,
                                                      int* __restrict__ pairs) {
    __shared__ int lbase[NB];
    __shared__ int lcur[NB];
    for (int i = threadIdx.x; i < NB; i += 256) {
        lbase[i] = bh[(size_t)blockIdx.x * NB + i];
        lcur[i] = 0;
    }
    __syncthreads();
    const int e0 = blockIdx.x * CHUNK, e1 = e0 + CHUNK;
    for (int e = e0 + threadIdx.x; e < e1; e += 256) {
        int c = ei[N_EDGES + e];
        int r = ei[e];
        int b = c >> 7;
        int off = atomicAdd(&lcur[b], 1);
        pairs[lbase[b] + off] = r | ((c & 127) << 17);
    }
}

// ---------- pass 4: per-bucket CSR build (coalesced adj writes) + offs + dis ----------
__global__ __launch_bounds__(256) void csr_kernel(const int* __restrict__ pairs,
                                                  const int* __restrict__ boff,
                                                  int* __restrict__ adj,
                                                  int* __restrict__ offs,
                                                  float* __restrict__ dis) {
    __shared__ int cnt[128];
    __shared__ int sc[128];
    __shared__ int base[128];
    __shared__ int cur[128];
    const int tid = threadIdx.x;
    const int b = blockIdx.x;
    const int beg = boff[b], end = boff[b + 1];
    if (tid < 128) { cnt[tid] = 0; cur[tid] = 0; }
    __syncthreads();
    for (int e = beg + tid; e < end; e += 256)
        atomicAdd(&cnt[pairs[e] >> 17], 1);
    __syncthreads();
    if (tid < 128) sc[tid] = cnt[tid];
    __syncthreads();
    for (int d = 1; d < 128; d <<= 1) {
        int t = (tid >= d && tid < 128) ? sc[tid - d] : 0;
        __syncthreads();
        if (tid < 128) sc[tid] += t;
        __syncthreads();
    }
    if (tid < 128) base[tid] = beg + sc[tid] - cnt[tid];   // exclusive + bucket base
    __syncthreads();
    for (int e = beg + tid; e < end; e += 256) {
        int v = pairs[e];
        int lc = v >> 17;
        int o = atomicAdd(&cur[lc], 1);
        adj[base[lc] + o] = v & 131071;
    }
    const int n = (b << 7) + tid;
    if (tid < 128 && n < N_NODES) {
        offs[n] = base[tid];
        dis[n] = rsqrtf((float)cnt[tid] + 1.0f);           // +1 = self-loop
    }
    if (b == 0 && tid == 0) offs[N_NODES] = N_EDGES;
}

// ---------- mm1: p = bf16(dis * (x @ W1)), 32-row LDS tile, padded (no bank conflicts) ----------
#define MM1_ROWS 32
#define XS_LD    132                       // 128 + 4 pad floats -> bank shift 4/row
__global__ __launch_bounds__(256) void mm1_kernel(const float* __restrict__ x,
                                                  const float* __restrict__ W1,
                                                  const float* __restrict__ dis,
                                                  unsigned short* __restrict__ p) {
    __shared__ float xs[MM1_ROWS * XS_LD]; // 16.9 KB
    __shared__ float ws[F_INP * HID];      // 32 KB
    for (int i = threadIdx.x; i < F_INP * HID / 4; i += 256)
        ((float4*)ws)[i] = ((const float4*)W1)[i];
    const int row_base = blockIdx.x * MM1_ROWS;
    for (int i = threadIdx.x; i < MM1_ROWS * (F_INP / 4); i += 256) {
        int r = i >> 5, c4 = i & 31;
        int gr = row_base + r;
        float4 v = make_float4(0.f, 0.f, 0.f, 0.f);
        if (gr < N_NODES) v = *(const float4*)(x + (size_t)gr * F_INP + c4 * 4);
        *(float4*)(xs + r * XS_LD + c4 * 4) = v;
    }
    __syncthreads();
    const int tx = threadIdx.x & 15;
    const int ty = threadIdx.x >> 4;
    float acc[2][4] = {};
#pragma unroll 4
    for (int k = 0; k < F_INP; k += 4) {
        float4 a0 = *(const float4*)(xs + ty * XS_LD + k);
        float4 a1 = *(const float4*)(xs + (ty + 16) * XS_LD + k);
        float4 w0 = *(const float4*)(ws + (k + 0) * HID + tx * 4);
        float4 w1 = *(const float4*)(ws + (k + 1) * HID + tx * 4);
        float4 w2 = *(const float4*)(ws + (k + 2) * HID + tx * 4);
        float4 w3 = *(const float4*)(ws + (k + 3) * HID + tx * 4);
        acc[0][0] += a0.x * w0.x + a0.y * w1.x + a0.z * w2.x + a0.w * w3.x;
        acc[0][1] += a0.x * w0.y + a0.y * w1.y + a0.z * w2.y + a0.w * w3.y;
        acc[0][2] += a0.x * w0.z + a0.y * w1.z + a0.z * w2.z + a0.w * w3.z;
        acc[0][3] += a0.x * w0.w + a0.y * w1.w + a0.z * w2.w + a0.w * w3.w;
        acc[1][0] += a1.x * w0.x + a1.y * w1.x + a1.z * w2.x + a1.w * w3.x;
        acc[1][1] += a1.x * w0.y + a1.y * w1.y + a1.z * w2.y + a1.w * w3.y;
        acc[1][2] += a1.x * w0.z + a1.y * w1.z + a1.z * w2.z + a1.w * w3.z;
        acc[1][3] += a1.x * w0.w + a1.y * w1.w + a1.z * w2.w + a1.w * w3.w;
    }
#pragma unroll
    for (int i = 0; i < 2; ++i) {
        int rr = row_base + ty + 16 * i;
        if (rr < N_NODES) {
            float d = dis[rr];
            ushort4 o;
            o.x = f2bf(d * acc[i][0]);
            o.y = f2bf(d * acc[i][1]);
            o.z = f2bf(d * acc[i][2]);
            o.w = f2bf(d * acc[i][3]);
            *(ushort4*)(p + (size_t)rr * HID + tx * 4) = o;
        }
    }
}

// ---------- mm2: p = bf16(dis * (h @ W2)), 64-row bf16 tile, padded ----------
#define HS_LD 72                            // 64 + 8 pad bf16 -> 144 B/row, bank shift 4
__global__ __launch_bounds__(256) void mm2_kernel(const unsigned short* __restrict__ hb,
                                                  const float* __restrict__ W2,
                                                  const float* __restrict__ dis,
                                                  unsigned short* __restrict__ p) {
    __shared__ unsigned short hs[64 * HS_LD];  // 9.2 KB
    __shared__ float ws[HID * HID];            // 16 KB
    for (int i = threadIdx.x; i < HID * HID / 4; i += 256)
        ((float4*)ws)[i] = ((const float4*)W2)[i];
    const int row_base = blockIdx.x * 64;
    for (int i = threadIdx.x; i < 64 * (HID / 8); i += 256) {
        int r = i >> 3, c8 = i & 7;
        int gr = row_base + r;
        uint4 v = make_uint4(0u, 0u, 0u, 0u);
        if (gr < N_NODES) v = *(const uint4*)(hb + (size_t)gr * HID + c8 * 8);
        *(uint4*)(hs + r * HS_LD + c8 * 8) = v;
    }
    __syncthreads();
    const int tx = threadIdx.x & 15;
    const int ty = threadIdx.x >> 4;
    float acc[4][4] = {};
#pragma unroll 2
    for (int k = 0; k < HID; k += 8) {
        uint4 a[4];
#pragma unroll
        for (int i = 0; i < 4; ++i)
            a[i] = *(const uint4*)(hs + (ty + 16 * i) * HS_LD + k);
        float4 w[8];
#pragma unroll
        for (int m = 0; m < 8; ++m)
            w[m] = *(const float4*)(ws + (k + m) * HID + tx * 4);
#pragma unroll
        for (int i = 0; i < 4; ++i) {
            float h0 = bf_lo(a[i].x), h1 = bf_hi(a[i].x);
            float h2 = bf_lo(a[i].y), h3 = bf_hi(a[i].y);
            float h4 = bf_lo(a[i].z), h5 = bf_hi(a[i].z);
            float h6 = bf_lo(a[i].w), h7 = bf_hi(a[i].w);
            acc[i][0] += h0 * w[0].x + h1 * w[1].x + h2 * w[2].x + h3 * w[3].x
                       + h4 * w[4].x + h5 * w[5].x + h6 * w[6].x + h7 * w[7].x;
            acc[i][1] += h0 * w[0].y + h1 * w[1].y + h2 * w[2].y + h3 * w[3].y
                       + h4 * w[4].y + h5 * w[5].y + h6 * w[6].y + h7 * w[7].y;
            acc[i][2] += h0 * w[0].z + h1 * w[1].z + h2 * w[2].z + h3 * w[3].z
                       + h4 * w[4].z + h5 * w[5].z + h6 * w[6].z + h7 * w[7].z;
            acc[i][3] += h0 * w[0].w + h1 * w[1].w + h2 * w[2].w + h3 * w[3].w
                       + h4 * w[4].w + h5 * w[5].w + h6 * w[6].w + h7 * w[7].w;
        }
    }
#pragma unroll
    for (int i = 0; i < 4; ++i) {
        int rr = row_base + ty + 16 * i;
        if (rr < N_NODES) {
            float d = dis[rr];
            ushort4 o;
            o.x = f2bf(d * acc[i][0]);
            o.y = f2bf(d * acc[i][1]);
            o.z = f2bf(d * acc[i][2]);
            o.w = f2bf(d * acc[i][3]);
            *(ushort4*)(p + (size_t)rr * HID + tx * 4) = o;
        }
    }
}

// ---------- gather core: 32-edge batches (4 loads in flight) + adj prefetch
//            + single masked 32-wide tail batch ----------
// lane L: q = L>>3 (row slot), g = L&7 (feature octet, feats 8g..8g+7)
__device__ __forceinline__ float gather_node(const unsigned short* __restrict__ pg,
                                             const int* __restrict__ adj,
                                             int c, int beg, int end, int q) {
    float acc[8];
    {   // self-loop row, counted once via q==0 lanes
        uint4 s = *(const uint4*)(pg + (size_t)c * HID);
        float sm = (q == 0) ? 1.f : 0.f;
        acc[0] = sm * bf_lo(s.x); acc[1] = sm * bf_hi(s.x);
        acc[2] = sm * bf_lo(s.y); acc[3] = sm * bf_hi(s.y);
        acc[4] = sm * bf_lo(s.z); acc[5] = sm * bf_hi(s.z);
        acc[6] = sm * bf_lo(s.w); acc[7] = sm * bf_hi(s.w);
    }
    int e = beg;
    const int nfull = (end - beg) >> 5;
    int r0, r1, r2, r3;
    if (nfull > 0) {
        r0 = adj[e + q]; r1 = adj[e + 8 + q]; r2 = adj[e + 16 + q]; r3 = adj[e + 24 + q];
    }
    for (int it = 0; it < nfull; ++it) {
        uint4 v0 = *(const uint4*)(pg + (size_t)r0 * HID);
        uint4 v1 = *(const uint4*)(pg + (size_t)r1 * HID);
        uint4 v2 = *(const uint4*)(pg + (size_t)r2 * HID);
        uint4 v3 = *(const uint4*)(pg + (size_t)r3 * HID);
        e += 32;
        if (it + 1 < nfull) {   // prefetch next batch's indices (overlaps row latency)
            r0 = adj[e + q]; r1 = adj[e + 8 + q]; r2 = adj[e + 16 + q]; r3 = adj[e + 24 + q];
        }
        acc[0] += (bf_lo(v0.x) + bf_lo(v1.x)) + (bf_lo(v2.x) + bf_lo(v3.x));
        acc[1] += (bf_hi(v0.x) + bf_hi(v1.x)) + (bf_hi(v2.x) + bf_hi(v3.x));
        acc[2] += (bf_lo(v0.y) + bf_lo(v1.y)) + (bf_lo(v2.y) + bf_lo(v3.y));
        acc[3] += (bf_hi(v0.y) + bf_hi(v1.y)) + (bf_hi(v2.y) + bf_hi(v3.y));
        acc[4] += (bf_lo(v0.z) + bf_lo(v1.z)) + (bf_lo(v2.z) + bf_lo(v3.z));
        acc[5] += (bf_hi(v0.z) + bf_hi(v1.z)) + (bf_hi(v2.z) + bf_hi(v3.z));
        acc[6] += (bf_lo(v0.w) + bf_lo(v1.w)) + (bf_lo(v2.w) + bf_lo(v3.w));
        acc[7] += (bf_hi(v0.w) + bf_hi(v1.w)) + (bf_hi(v2.w) + bf_hi(v3.w));
    }
    if (e < end) {   // one masked batch covers all <=31 remaining edges (4 loads in flight)
        const int l = end - 1;
        int i0 = e + q, i1 = e + 8 + q, i2 = e + 16 + q, i3 = e + 24 + q;
        int t0 = adj[min(i0, l)], t1 = adj[min(i1, l)], t2 = adj[min(i2, l)], t3 = adj[min(i3, l)];
        float m0 = (i0 < end) ? 1.f : 0.f;
        float m1 = (i1 < end) ? 1.f : 0.f;
        float m2 = (i2 < end) ? 1.f : 0.f;
        float m3 = (i3 < end) ? 1.f : 0.f;
        uint4 v0 = *(const uint4*)(pg + (size_t)t0 * HID);
        uint4 v1 = *(const uint4*)(pg + (size_t)t1 * HID);
        uint4 v2 = *(const uint4*)(pg + (size_t)t2 * HID);
        uint4 v3 = *(const uint4*)(pg + (size_t)t3 * HID);
        acc[0] = fmaf(m0, bf_lo(v0.x), fmaf(m1, bf_lo(v1.x), fmaf(m2, bf_lo(v2.x), fmaf(m3, bf_lo(v3.x), acc[0]))));
        acc[1] = fmaf(m0, bf_hi(v0.x), fmaf(m1, bf_hi(v1.x), fmaf(m2, bf_hi(v2.x), fmaf(m3, bf_hi(v3.x), acc[1]))));
        acc[2] = fmaf(m0, bf_lo(v0.y), fmaf(m1, bf_lo(v1.y), fmaf(m2, bf_lo(v2.y), fmaf(m3, bf_lo(v3.y), acc[2]))));
        acc[3] = fmaf(m0, bf_hi(v0.y), fmaf(m1, bf_hi(v1.y), fmaf(m2, bf_hi(v2.y), fmaf(m3, bf_hi(v3.y), acc[3]))));
        acc[4] = fmaf(m0, bf_lo(v0.z), fmaf(m1, bf_lo(v1.z), fmaf(m2, bf_lo(v2.z), fmaf(m3, bf_lo(v3.z), acc[4]))));
        acc[5] = fmaf(m0, bf_hi(v0.z), fmaf(m1, bf_hi(v1.z), fmaf(m2, bf_hi(v2.z), fmaf(m3, bf_hi(v3.z), acc[5]))));
        acc[6] = fmaf(m0, bf_lo(v0.w), fmaf(m1, bf_lo(v1.w), fmaf(m2, bf_lo(v2.w), fmaf(m3, bf_lo(v3.w), acc[6]))));
        acc[7] = fmaf(m0, bf_hi(v0.w), fmaf(m1, bf_hi(v1.w), fmaf(m2, bf_hi(v2.w), fmaf(m3, bf_hi(v3.w), acc[7]))));
    }
    // select-tree reduction over q bits (lane ends with feature 8g+q)
    const bool q0 = (q & 1) != 0, q1 = (q & 2) != 0, q2 = (q & 4) != 0;
    float b0 = (q0 ? acc[1] : acc[0]) + __shfl_xor(q0 ? acc[0] : acc[1], 8, 64);
    float b1 = (q0 ? acc[3] : acc[2]) + __shfl_xor(q0 ? acc[2] : acc[3], 8, 64);
    float b2 = (q0 ? acc[5] : acc[4]) + __shfl_xor(q0 ? acc[4] : acc[5], 8, 64);
    float b3 = (q0 ? acc[7] : acc[6]) + __shfl_xor(q0 ? acc[6] : acc[7], 8, 64);
    float c0 = (q1 ? b1 : b0) + __shfl_xor(q1 ? b0 : b1, 16, 64);
    float c1 = (q1 ? b3 : b2) + __shfl_xor(q1 ? b2 : b3, 16, 64);
    return (q2 ? c1 : c0) + __shfl_xor(q2 ? c0 : c1, 32, 64);
}

// ---------- gather1: hb = bf16(relu(dis[c]*(p[c]+sum p[r]) + b1)), contiguous chunks ----------
__global__ __launch_bounds__(256) void gather1_kernel(const unsigned short* __restrict__ p,
                                                      const int* __restrict__ adj,
                                                      const int* __restrict__ offs,
                                                      const float* __restrict__ dis,
                                                      const float* __restrict__ b1,
                                                      unsigned short* __restrict__ hb) {
    const int lane = threadIdx.x & 63;
    const int q = lane >> 3, g = lane & 7;
    const unsigned short* pg = p + g * 8;
    const int gwave = (blockIdx.x * blockDim.x + threadIdx.x) >> 6;
    const int nwaves = (gridDim.x * blockDim.x) >> 6;
    const int per = (N_NODES + nwaves - 1) / nwaves;
    const int c0 = gwave * per;
    const int c1 = min(N_NODES, c0 + per);
    const float bj = b1[g * 8 + q];
    for (int c = c0; c < c1; ++c) {
        const int beg = offs[c], end = offs[c + 1];
        float val = gather_node(pg, adj, c, beg, end, q);
        hb[(size_t)c * HID + g * 8 + q] = f2bf(fmaxf(dis[c] * val + bj, 0.f));
    }
}

// ---------- gather2 + mean-pool numerator (run-length atomics over sorted batch) ----------
__global__ __launch_bounds__(256) void gather2_kernel(const unsigned short* __restrict__ p,
                                                      const int* __restrict__ adj,
                                                      const int* __restrict__ offs,
                                                      const float* __restrict__ dis,
                                                      const float* __restrict__ b2,
                                                      const int* __restrict__ batch,
                                                      float* __restrict__ sums) {
    const int lane = threadIdx.x & 63;
    const int q = lane >> 3, g = lane & 7;
    const unsigned short* pg = p + g * 8;
    const int gwave = (blockIdx.x * blockDim.x + threadIdx.x) >> 6;
    const int nwaves = (gridDim.x * blockDim.x) >> 6;
    const int per = (N_NODES + nwaves - 1) / nwaves;
    const int c0 = gwave * per;
    const int c1 = min(N_NODES, c0 + per);
    const float bj = b2[g * 8 + q];
    const int feat = g * 8 + q;
    float part = 0.f;
    int gc = -1;
    for (int c = c0; c < c1; ++c) {
        const int beg = offs[c], end = offs[c + 1];
        float val = gather_node(pg, adj, c, beg, end, q);
        float v = fmaxf(dis[c] * val + bj, 0.f);
        int gid = batch[c];                       // wave-uniform
        if (gid != gc) {
            if (gc >= 0) atomicAdd(&sums[(size_t)gc * HID + feat], part);
            part = 0.f;
            gc = gid;
        }
        part += v;
    }
    if (gc >= 0) atomicAdd(&sums[(size_t)gc * HID + feat], part);
}

// ---------- final FC (counts fused via binary search on sorted batch) ----------
__global__ void fc_kernel(const float* __restrict__ sums, const int* __restrict__ batch,
                          const float* __restrict__ Wfc, const float* __restrict__ bfc,
                          float* __restrict__ out) {
    const int g = blockIdx.x;
    const int j = threadIdx.x;
    int lo = 0, hi = N_NODES;
    while (lo < hi) { int m = (lo + hi) >> 1; if (batch[m] < g) lo = m + 1; else hi = m; }
    const int l0 = lo;
    lo = 0; hi = N_NODES;
    while (lo < hi) { int m = (lo + hi) >> 1; if (batch[m] < g + 1) lo = m + 1; else hi = m; }
    float cnt = fmaxf((float)(lo - l0), 1.0f);
    float pj = sums[(size_t)g * HID + j] / cnt;
    float a0 = pj * Wfc[j * N_CLASSES + 0];
    float a1 = pj * Wfc[j * N_CLASSES + 1];
    for (int off = 32; off > 0; off >>= 1) {
        a0 += __shfl_down(a0, off, 64);
        a1 += __shfl_down(a1, off, 64);
    }
    if (j == 0) {
        out[g * N_CLASSES + 0] = a0 + bfc[0];
        out[g * N_CLASSES + 1] = a1 + bfc[1];
    }
}

extern "C" void kernel_launch(void* const* d_in, const int* in_sizes, int n_in,
                              void* d_out, int out_size, void* d_ws, size_t ws_size,
                              hipStream_t stream) {
    const float* x     = (const float*)d_in[0];
    const int*   ei    = (const int*)d_in[1];   // [2,E]: row=ei[0:E], col=ei[E:2E]
    const int*   batch = (const int*)d_in[2];
    const float* W1    = (const float*)d_in[3];
    const float* b1    = (const float*)d_in[4];
    const float* W2    = (const float*)d_in[5];
    const float* b2    = (const float*)d_in[6];
    const float* Wfc   = (const float*)d_in[7];
    const float* bfc   = (const float*)d_in[8];
    float* out = (float*)d_out;

    char* ws = (char*)d_ws;
    size_t off = 0;
    auto alloc = [&](size_t bytes) -> void* {
        void* pp = ws + off;
        off += (bytes + 255) & ~(size_t)255;
        return pp;
    };
    int*   bcnt   = (int*)alloc((size_t)NB * 4);
    int*   boff   = (int*)alloc((size_t)(NB + 1) * 4);
    int*   bh     = (int*)alloc((size_t)SCAT_BLOCKS * NB * 4);   // per-block hist -> bases
    float* dis    = (float*)alloc((size_t)N_NODES * 4);
    int*   pairs  = (int*)alloc((size_t)N_EDGES * 4);
    int*   adj    = (int*)alloc((size_t)N_EDGES * 4);
    int*   offs   = (int*)alloc((size_t)(N_NODES + 1) * 4);
    unsigned short* p  = (unsigned short*)alloc((size_t)N_NODES * HID * 2);
    unsigned short* hb = (unsigned short*)alloc((size_t)N_NODES * HID * 2);
    float* sums   = (float*)alloc((size_t)N_GRAPHS * HID * 4);

    hipMemsetAsync(bcnt, 0, (size_t)NB * 4, stream);
    hipMemsetAsync(sums, 0, (size_t)N_GRAPHS * HID * 4, stream);

    hist_kernel<<<SCAT_BLOCKS, 256, 0, stream>>>(ei, bcnt, bh);
    scan_kernel<<<1, 1024, 0, stream>>>(bcnt, boff);
    bbase_kernel<<<(NB + 63) / 64, 64, 0, stream>>>(bh, boff);
    scatter_kernel<<<SCAT_BLOCKS, 256, 0, stream>>>(ei, bh, pairs);
    csr_kernel<<<NB, 256, 0, stream>>>(pairs, boff, adj, offs, dis);
    mm1_kernel<<<(N_NODES + MM1_ROWS - 1) / MM1_ROWS, 256, 0, stream>>>(x, W1, dis, p);
    gather1_kernel<<<2048, 256, 0, stream>>>(p, adj, offs, dis, b1, hb);
    mm2_kernel<<<(N_NODES + 63) / 64, 256, 0, stream>>>(hb, W2, dis, p);
    gather2_kernel<<<2048, 256, 0, stream>>>(p, adj, offs, dis, b2, batch, sums);
    fc_kernel<<<N_GRAPHS, 64, 0, stream>>>(sums, batch, Wfc, bfc, out);
}

// Round 12
// 354.123 us; speedup vs baseline: 1.1635x; 1.1352x over previous
//
#include <hip/hip_runtime.h>

#define N_NODES   100000
#define N_EDGES   3200000
#define F_INP     128
#define HID       64
#define N_GRAPHS  512
#define N_CLASSES 2
#define NB        782                      // ceil(N/128) buckets of 128 target nodes
#define SCAT_BLOCKS 256
#define CHUNK     (N_EDGES / SCAT_BLOCKS)  // 12500, exact

// bf16 helpers: RTN encode; decode low/high halves of a packed u32
__device__ __forceinline__ unsigned short f2bf(float f) {
    unsigned int u = __float_as_uint(f);
    return (unsigned short)((u + 0x7FFFu + ((u >> 16) & 1u)) >> 16);
}
__device__ __forceinline__ float bf_lo(unsigned int u) { return __uint_as_float(u << 16); }
__device__ __forceinline__ float bf_hi(unsigned int u) { return __uint_as_float(u & 0xFFFF0000u); }

// ---------- pass 1: per-block bucket histogram -> bh + global bcnt ----------
__global__ __launch_bounds__(256) void hist_kernel(const int* __restrict__ ei,
                                                   int* __restrict__ bcnt,
                                                   int* __restrict__ bh) {
    __shared__ int hist[NB];
    for (int i = threadIdx.x; i < NB; i += 256) hist[i] = 0;
    __syncthreads();
    const int e0 = blockIdx.x * CHUNK, e1 = e0 + CHUNK;
    for (int e = e0 + threadIdx.x; e < e1; e += 256)
        atomicAdd(&hist[ei[N_EDGES + e] >> 7], 1);
    __syncthreads();
    for (int i = threadIdx.x; i < NB; i += 256) {
        int v = hist[i];
        bh[(size_t)blockIdx.x * NB + i] = v;
        if (v) atomicAdd(&bcnt[i], v);
    }
}

// ---------- pass 2: exclusive scan over 782 buckets (one block) ----------
__global__ __launch_bounds__(1024) void scan_kernel(const int* __restrict__ bcnt,
                                                    int* __restrict__ boff) {
    __shared__ int s[1024];
    const int tid = threadIdx.x;
    const int v = (tid < NB) ? bcnt[tid] : 0;
    s[tid] = v;
    __syncthreads();
    for (int d = 1; d < 1024; d <<= 1) {
        int t = (tid >= d) ? s[tid - d] : 0;
        __syncthreads();
        s[tid] += t;
        __syncthreads();
    }
    if (tid <= NB) boff[tid] = s[tid] - v;   // exclusive; tid==NB -> N_EDGES
}

// ---------- pass 2b: per-(block,bucket) bases, coalesced: thread = bucket ----------
__global__ __launch_bounds__(64) void bbase_kernel(int* __restrict__ bh,
                                                   const int* __restrict__ boff) {
    const int b = blockIdx.x * 64 + threadIdx.x;
    if (b >= NB) return;
    int base = boff[b];
    for (int i = 0; i < SCAT_BLOCKS; i += 8) {
        int v[8];
#pragma unroll
        for (int j = 0; j < 8; ++j) v[j] = bh[(size_t)(i + j) * NB + b];
#pragma unroll
        for (int j = 0; j < 8; ++j) { bh[(size_t)(i + j) * NB + b] = base; base += v[j]; }
    }
}

// ---------- pass 3: single-pass localized scatter using precomputed bases ----------
// pairs[e] = r | ((c & 127) << 17);  r < 2^17
__global__ __launch_bounds__(256) void scatter_kernel(const int* __restrict__ ei,
                                                      const int* __restrict__ bh,
                                                      int* __restrict__ pairs) {
    __shared__ int lbase[NB];
    __shared__ int lcur[NB];
    for (int i = threadIdx.x; i < NB; i += 256) {
        lbase[i] = bh[(size_t)blockIdx.x * NB + i];
        lcur[i] = 0;
    }
    __syncthreads();
    const int e0 = blockIdx.x * CHUNK, e1 = e0 + CHUNK;
    for (int e = e0 + threadIdx.x; e < e1; e += 256) {
        int c = ei[N_EDGES + e];
        int r = ei[e];
        int b = c >> 7;
        int off = atomicAdd(&lcur[b], 1);
        pairs[lbase[b] + off] = r | ((c & 127) << 17);
    }
}

// ---------- pass 4: per-bucket CSR build (coalesced adj writes) + offs + dis ----------
__global__ __launch_bounds__(256) void csr_kernel(const int* __restrict__ pairs,
                                                  const int* __restrict__ boff,
                                                  int* __restrict__ adj,
                                                  int* __restrict__ offs,
                                                  float* __restrict__ dis) {
    __shared__ int cnt[128];
    __shared__ int sc[128];
    __shared__ int base[128];
    __shared__ int cur[128];
    const int tid = threadIdx.x;
    const int b = blockIdx.x;
    const int beg = boff[b], end = boff[b + 1];
    if (tid < 128) { cnt[tid] = 0; cur[tid] = 0; }
    __syncthreads();
    for (int e = beg + tid; e < end; e += 256)
        atomicAdd(&cnt[pairs[e] >> 17], 1);
    __syncthreads();
    if (tid < 128) sc[tid] = cnt[tid];
    __syncthreads();
    for (int d = 1; d < 128; d <<= 1) {
        int t = (tid >= d && tid < 128) ? sc[tid - d] : 0;
        __syncthreads();
        if (tid < 128) sc[tid] += t;
        __syncthreads();
    }
    if (tid < 128) base[tid] = beg + sc[tid] - cnt[tid];   // exclusive + bucket base
    __syncthreads();
    for (int e = beg + tid; e < end; e += 256) {
        int v = pairs[e];
        int lc = v >> 17;
        int o = atomicAdd(&cur[lc], 1);
        adj[base[lc] + o] = v & 131071;
    }
    const int n = (b << 7) + tid;
    if (tid < 128 && n < N_NODES) {
        offs[n] = base[tid];
        dis[n] = rsqrtf((float)cnt[tid] + 1.0f);           // +1 = self-loop
    }
    if (b == 0 && tid == 0) offs[N_NODES] = N_EDGES;
}

// ---------- mm1: p = bf16(dis * (x @ W1)), 32-row LDS tile, padded (no bank conflicts) ----------
#define MM1_ROWS 32
#define XS_LD    132                       // 128 + 4 pad floats -> bank shift 4/row
__global__ __launch_bounds__(256) void mm1_kernel(const float* __restrict__ x,
                                                  const float* __restrict__ W1,
                                                  const float* __restrict__ dis,
                                                  unsigned short* __restrict__ p) {
    __shared__ float xs[MM1_ROWS * XS_LD]; // 16.9 KB
    __shared__ float ws[F_INP * HID];      // 32 KB
    for (int i = threadIdx.x; i < F_INP * HID / 4; i += 256)
        ((float4*)ws)[i] = ((const float4*)W1)[i];
    const int row_base = blockIdx.x * MM1_ROWS;
    for (int i = threadIdx.x; i < MM1_ROWS * (F_INP / 4); i += 256) {
        int r = i >> 5, c4 = i & 31;
        int gr = row_base + r;
        float4 v = make_float4(0.f, 0.f, 0.f, 0.f);
        if (gr < N_NODES) v = *(const float4*)(x + (size_t)gr * F_INP + c4 * 4);
        *(float4*)(xs + r * XS_LD + c4 * 4) = v;
    }
    __syncthreads();
    const int tx = threadIdx.x & 15;
    const int ty = threadIdx.x >> 4;
    float acc[2][4] = {};
#pragma unroll 4
    for (int k = 0; k < F_INP; k += 4) {
        float4 a0 = *(const float4*)(xs + ty * XS_LD + k);
        float4 a1 = *(const float4*)(xs + (ty + 16) * XS_LD + k);
        float4 w0 = *(const float4*)(ws + (k + 0) * HID + tx * 4);
        float4 w1 = *(const float4*)(ws + (k + 1) * HID + tx * 4);
        float4 w2 = *(const float4*)(ws + (k + 2) * HID + tx * 4);
        float4 w3 = *(const float4*)(ws + (k + 3) * HID + tx * 4);
        acc[0][0] += a0.x * w0.x + a0.y * w1.x + a0.z * w2.x + a0.w * w3.x;
        acc[0][1] += a0.x * w0.y + a0.y * w1.y + a0.z * w2.y + a0.w * w3.y;
        acc[0][2] += a0.x * w0.z + a0.y * w1.z + a0.z * w2.z + a0.w * w3.z;
        acc[0][3] += a0.x * w0.w + a0.y * w1.w + a0.z * w2.w + a0.w * w3.w;
        acc[1][0] += a1.x * w0.x + a1.y * w1.x + a1.z * w2.x + a1.w * w3.x;
        acc[1][1] += a1.x * w0.y + a1.y * w1.y + a1.z * w2.y + a1.w * w3.y;
        acc[1][2] += a1.x * w0.z + a1.y * w1.z + a1.z * w2.z + a1.w * w3.z;
        acc[1][3] += a1.x * w0.w + a1.y * w1.w + a1.z * w2.w + a1.w * w3.w;
    }
#pragma unroll
    for (int i = 0; i < 2; ++i) {
        int rr = row_base + ty + 16 * i;
        if (rr < N_NODES) {
            float d = dis[rr];
            ushort4 o;
            o.x = f2bf(d * acc[i][0]);
            o.y = f2bf(d * acc[i][1]);
            o.z = f2bf(d * acc[i][2]);
            o.w = f2bf(d * acc[i][3]);
            *(ushort4*)(p + (size_t)rr * HID + tx * 4) = o;
        }
    }
}

// ---------- mm2: p = bf16(dis * (h @ W2)), 64-row bf16 tile, padded ----------
#define HS_LD 72                            // 64 + 8 pad bf16 -> 144 B/row, bank shift 4
__global__ __launch_bounds__(256) void mm2_kernel(const unsigned short* __restrict__ hb,
                                                  const float* __restrict__ W2,
                                                  const float* __restrict__ dis,
                                                  unsigned short* __restrict__ p) {
    __shared__ unsigned short hs[64 * HS_LD];  // 9.2 KB
    __shared__ float ws[HID * HID];            // 16 KB
    for (int i = threadIdx.x; i < HID * HID / 4; i += 256)
        ((float4*)ws)[i] = ((const float4*)W2)[i];
    const int row_base = blockIdx.x * 64;
    for (int i = threadIdx.x; i < 64 * (HID / 8); i += 256) {
        int r = i >> 3, c8 = i & 7;
        int gr = row_base + r;
        uint4 v = make_uint4(0u, 0u, 0u, 0u);
        if (gr < N_NODES) v = *(const uint4*)(hb + (size_t)gr * HID + c8 * 8);
        *(uint4*)(hs + r * HS_LD + c8 * 8) = v;
    }
    __syncthreads();
    const int tx = threadIdx.x & 15;
    const int ty = threadIdx.x >> 4;
    float acc[4][4] = {};
#pragma unroll 2
    for (int k = 0; k < HID; k += 8) {
        uint4 a[4];
#pragma unroll
        for (int i = 0; i < 4; ++i)
            a[i] = *(const uint4*)(hs + (ty + 16 * i) * HS_LD + k);
        float4 w[8];
#pragma unroll
        for (int m = 0; m < 8; ++m)
            w[m] = *(const float4*)(ws + (k + m) * HID + tx * 4);
#pragma unroll
        for (int i = 0; i < 4; ++i) {
            float h0 = bf_lo(a[i].x), h1 = bf_hi(a[i].x);
            float h2 = bf_lo(a[i].y), h3 = bf_hi(a[i].y);
            float h4 = bf_lo(a[i].z), h5 = bf_hi(a[i].z);
            float h6 = bf_lo(a[i].w), h7 = bf_hi(a[i].w);
            acc[i][0] += h0 * w[0].x + h1 * w[1].x + h2 * w[2].x + h3 * w[3].x
                       + h4 * w[4].x + h5 * w[5].x + h6 * w[6].x + h7 * w[7].x;
            acc[i][1] += h0 * w[0].y + h1 * w[1].y + h2 * w[2].y + h3 * w[3].y
                       + h4 * w[4].y + h5 * w[5].y + h6 * w[6].y + h7 * w[7].y;
            acc[i][2] += h0 * w[0].z + h1 * w[1].z + h2 * w[2].z + h3 * w[3].z
                       + h4 * w[4].z + h5 * w[5].z + h6 * w[6].z + h7 * w[7].z;
            acc[i][3] += h0 * w[0].w + h1 * w[1].w + h2 * w[2].w + h3 * w[3].w
                       + h4 * w[4].w + h5 * w[5].w + h6 * w[6].w + h7 * w[7].w;
        }
    }
#pragma unroll
    for (int i = 0; i < 4; ++i) {
        int rr = row_base + ty + 16 * i;
        if (rr < N_NODES) {
            float d = dis[rr];
            ushort4 o;
            o.x = f2bf(d * acc[i][0]);
            o.y = f2bf(d * acc[i][1]);
            o.z = f2bf(d * acc[i][2]);
            o.w = f2bf(d * acc[i][3]);
            *(ushort4*)(p + (size_t)rr * HID + tx * 4) = o;
        }
    }
}

// ---------- round-8 gather core (empirical optimum): 32/16/masked-8 loops ----------
// lane L: q = L>>3 (row slot), g = L&7 (feature octet, feats 8g..8g+7)
__device__ __forceinline__ float gather_node(const unsigned short* __restrict__ p,
                                             const int* __restrict__ adj,
                                             int c, int beg, int end, int q, int g) {
    float acc[8];
    {   // self-loop row, counted once via q==0 lanes
        uint4 s = *(const uint4*)(p + (size_t)c * HID + g * 8);
        float sm = (q == 0) ? 1.f : 0.f;
        acc[0] = sm * bf_lo(s.x); acc[1] = sm * bf_hi(s.x);
        acc[2] = sm * bf_lo(s.y); acc[3] = sm * bf_hi(s.y);
        acc[4] = sm * bf_lo(s.z); acc[5] = sm * bf_hi(s.z);
        acc[6] = sm * bf_lo(s.w); acc[7] = sm * bf_hi(s.w);
    }
    int e = beg;
    for (; e + 32 <= end; e += 32) {            // 4 row-loads in flight
        int r0 = adj[e + q];
        int r1 = adj[e + 8 + q];
        int r2 = adj[e + 16 + q];
        int r3 = adj[e + 24 + q];
        uint4 v0 = *(const uint4*)(p + (size_t)r0 * HID + g * 8);
        uint4 v1 = *(const uint4*)(p + (size_t)r1 * HID + g * 8);
        uint4 v2 = *(const uint4*)(p + (size_t)r2 * HID + g * 8);
        uint4 v3 = *(const uint4*)(p + (size_t)r3 * HID + g * 8);
        acc[0] += (bf_lo(v0.x) + bf_lo(v1.x)) + (bf_lo(v2.x) + bf_lo(v3.x));
        acc[1] += (bf_hi(v0.x) + bf_hi(v1.x)) + (bf_hi(v2.x) + bf_hi(v3.x));
        acc[2] += (bf_lo(v0.y) + bf_lo(v1.y)) + (bf_lo(v2.y) + bf_lo(v3.y));
        acc[3] += (bf_hi(v0.y) + bf_hi(v1.y)) + (bf_hi(v2.y) + bf_hi(v3.y));
        acc[4] += (bf_lo(v0.z) + bf_lo(v1.z)) + (bf_lo(v2.z) + bf_lo(v3.z));
        acc[5] += (bf_hi(v0.z) + bf_hi(v1.z)) + (bf_hi(v2.z) + bf_hi(v3.z));
        acc[6] += (bf_lo(v0.w) + bf_lo(v1.w)) + (bf_lo(v2.w) + bf_lo(v3.w));
        acc[7] += (bf_hi(v0.w) + bf_hi(v1.w)) + (bf_hi(v2.w) + bf_hi(v3.w));
    }
    for (; e + 16 <= end; e += 16) {
        int r0 = adj[e + q];
        int r1 = adj[e + 8 + q];
        uint4 v0 = *(const uint4*)(p + (size_t)r0 * HID + g * 8);
        uint4 v1 = *(const uint4*)(p + (size_t)r1 * HID + g * 8);
        acc[0] += bf_lo(v0.x) + bf_lo(v1.x); acc[1] += bf_hi(v0.x) + bf_hi(v1.x);
        acc[2] += bf_lo(v0.y) + bf_lo(v1.y); acc[3] += bf_hi(v0.y) + bf_hi(v1.y);
        acc[4] += bf_lo(v0.z) + bf_lo(v1.z); acc[5] += bf_hi(v0.z) + bf_hi(v1.z);
        acc[6] += bf_lo(v0.w) + bf_lo(v1.w); acc[7] += bf_hi(v0.w) + bf_hi(v1.w);
    }
    for (; e < end; e += 8) {                   // masked tail
        int idx = e + q;
        int r = adj[min(idx, end - 1)];
        float m = (idx < end) ? 1.f : 0.f;
        uint4 v = *(const uint4*)(p + (size_t)r * HID + g * 8);
        acc[0] = fmaf(m, bf_lo(v.x), acc[0]); acc[1] = fmaf(m, bf_hi(v.x), acc[1]);
        acc[2] = fmaf(m, bf_lo(v.y), acc[2]); acc[3] = fmaf(m, bf_hi(v.y), acc[3]);
        acc[4] = fmaf(m, bf_lo(v.z), acc[4]); acc[5] = fmaf(m, bf_hi(v.z), acc[5]);
        acc[6] = fmaf(m, bf_lo(v.w), acc[6]); acc[7] = fmaf(m, bf_hi(v.w), acc[7]);
    }
    // select-tree reduction over q bits (lane ends with feature 8g+q)
    const bool q0 = (q & 1) != 0, q1 = (q & 2) != 0, q2 = (q & 4) != 0;
    float b0 = (q0 ? acc[1] : acc[0]) + __shfl_xor(q0 ? acc[0] : acc[1], 8, 64);
    float b1 = (q0 ? acc[3] : acc[2]) + __shfl_xor(q0 ? acc[2] : acc[3], 8, 64);
    float b2 = (q0 ? acc[5] : acc[4]) + __shfl_xor(q0 ? acc[4] : acc[5], 8, 64);
    float b3 = (q0 ? acc[7] : acc[6]) + __shfl_xor(q0 ? acc[6] : acc[7], 8, 64);
    float c0 = (q1 ? b1 : b0) + __shfl_xor(q1 ? b0 : b1, 16, 64);
    float c1 = (q1 ? b3 : b2) + __shfl_xor(q1 ? b2 : b3, 16, 64);
    return (q2 ? c1 : c0) + __shfl_xor(q2 ? c0 : c1, 32, 64);
}

// ---------- gather1: hb = bf16(relu(dis[c]*(p[c]+sum p[r]) + b1)), contiguous chunks ----------
__global__ __launch_bounds__(256) void gather1_kernel(const unsigned short* __restrict__ p,
                                                      const int* __restrict__ adj,
                                                      const int* __restrict__ offs,
                                                      const float* __restrict__ dis,
                                                      const float* __restrict__ b1,
                                                      unsigned short* __restrict__ hb) {
    const int lane = threadIdx.x & 63;
    const int q = lane >> 3, g = lane & 7;
    const int gwave = (blockIdx.x * blockDim.x + threadIdx.x) >> 6;
    const int nwaves = (gridDim.x * blockDim.x) >> 6;
    const int per = (N_NODES + nwaves - 1) / nwaves;
    const int c0 = gwave * per;
    const int c1 = min(N_NODES, c0 + per);
    const float bj = b1[g * 8 + q];
    for (int c = c0; c < c1; ++c) {
        const int beg = offs[c], end = offs[c + 1];
        float val = gather_node(p, adj, c, beg, end, q, g);
        hb[(size_t)c * HID + g * 8 + q] = f2bf(fmaxf(dis[c] * val + bj, 0.f));
    }
}

// ---------- gather2 + mean-pool numerator (run-length atomics over sorted batch) ----------
__global__ __launch_bounds__(256) void gather2_kernel(const unsigned short* __restrict__ p,
                                                      const int* __restrict__ adj,
                                                      const int* __restrict__ offs,
                                                      const float* __restrict__ dis,
                                                      const float* __restrict__ b2,
                                                      const int* __restrict__ batch,
                                                      float* __restrict__ sums) {
    const int lane = threadIdx.x & 63;
    const int q = lane >> 3, g = lane & 7;
    const int gwave = (blockIdx.x * blockDim.x + threadIdx.x) >> 6;
    const int nwaves = (gridDim.x * blockDim.x) >> 6;
    const int per = (N_NODES + nwaves - 1) / nwaves;
    const int c0 = gwave * per;
    const int c1 = min(N_NODES, c0 + per);
    const float bj = b2[g * 8 + q];
    const int feat = g * 8 + q;
    float part = 0.f;
    int gc = -1;
    for (int c = c0; c < c1; ++c) {
        const int beg = offs[c], end = offs[c + 1];
        float val = gather_node(p, adj, c, beg, end, q, g);
        float v = fmaxf(dis[c] * val + bj, 0.f);
        int gid = batch[c];                       // wave-uniform
        if (gid != gc) {
            if (gc >= 0) atomicAdd(&sums[(size_t)gc * HID + feat], part);
            part = 0.f;
            gc = gid;
        }
        part += v;
    }
    if (gc >= 0) atomicAdd(&sums[(size_t)gc * HID + feat], part);
}

// ---------- final FC (counts fused via binary search on sorted batch) ----------
__global__ void fc_kernel(const float* __restrict__ sums, const int* __restrict__ batch,
                          const float* __restrict__ Wfc, const float* __restrict__ bfc,
                          float* __restrict__ out) {
    const int g = blockIdx.x;
    const int j = threadIdx.x;
    int lo = 0, hi = N_NODES;
    while (lo < hi) { int m = (lo + hi) >> 1; if (batch[m] < g) lo = m + 1; else hi = m; }
    const int l0 = lo;
    lo = 0; hi = N_NODES;
    while (lo < hi) { int m = (lo + hi) >> 1; if (batch[m] < g + 1) lo = m + 1; else hi = m; }
    float cnt = fmaxf((float)(lo - l0), 1.0f);
    float pj = sums[(size_t)g * HID + j] / cnt;
    float a0 = pj * Wfc[j * N_CLASSES + 0];
    float a1 = pj * Wfc[j * N_CLASSES + 1];
    for (int off = 32; off > 0; off >>= 1) {
        a0 += __shfl_down(a0, off, 64);
        a1 += __shfl_down(a1, off, 64);
    }
    if (j == 0) {
        out[g * N_CLASSES + 0] = a0 + bfc[0];
        out[g * N_CLASSES + 1] = a1 + bfc[1];
    }
}

extern "C" void kernel_launch(void* const* d_in, const int* in_sizes, int n_in,
                              void* d_out, int out_size, void* d_ws, size_t ws_size,
                              hipStream_t stream) {
    const float* x     = (const float*)d_in[0];
    const int*   ei    = (const int*)d_in[1];   // [2,E]: row=ei[0:E], col=ei[E:2E]
    const int*   batch = (const int*)d_in[2];
    const float* W1    = (const float*)d_in[3];
    const float* b1    = (const float*)d_in[4];
    const float* W2    = (const float*)d_in[5];
    const float* b2    = (const float*)d_in[6];
    const float* Wfc   = (const float*)d_in[7];
    const float* bfc   = (const float*)d_in[8];
    float* out = (float*)d_out;

    char* ws = (char*)d_ws;
    size_t off = 0;
    auto alloc = [&](size_t bytes) -> void* {
        void* pp = ws + off;
        off += (bytes + 255) & ~(size_t)255;
        return pp;
    };
    int*   bcnt   = (int*)alloc((size_t)NB * 4);
    int*   boff   = (int*)alloc((size_t)(NB + 1) * 4);
    int*   bh     = (int*)alloc((size_t)SCAT_BLOCKS * NB * 4);   // per-block hist -> bases
    float* dis    = (float*)alloc((size_t)N_NODES * 4);
    int*   pairs  = (int*)alloc((size_t)N_EDGES * 4);
    int*   adj    = (int*)alloc((size_t)N_EDGES * 4);
    int*   offs   = (int*)alloc((size_t)(N_NODES + 1) * 4);
    unsigned short* p  = (unsigned short*)alloc((size_t)N_NODES * HID * 2);
    unsigned short* hb = (unsigned short*)alloc((size_t)N_NODES * HID * 2);
    float* sums   = (float*)alloc((size_t)N_GRAPHS * HID * 4);

    hipMemsetAsync(bcnt, 0, (size_t)NB * 4, stream);
    hipMemsetAsync(sums, 0, (size_t)N_GRAPHS * HID * 4, stream);

    hist_kernel<<<SCAT_BLOCKS, 256, 0, stream>>>(ei, bcnt, bh);
    scan_kernel<<<1, 1024, 0, stream>>>(bcnt, boff);
    bbase_kernel<<<(NB + 63) / 64, 64, 0, stream>>>(bh, boff);
    scatter_kernel<<<SCAT_BLOCKS, 256, 0, stream>>>(ei, bh, pairs);
    csr_kernel<<<NB, 256, 0, stream>>>(pairs, boff, adj, offs, dis);
    mm1_kernel<<<(N_NODES + MM1_ROWS - 1) / MM1_ROWS, 256, 0, stream>>>(x, W1, dis, p);
    gather1_kernel<<<2048, 256, 0, stream>>>(p, adj, offs, dis, b1, hb);
    mm2_kernel<<<(N_NODES + 63) / 64, 256, 0, stream>>>(hb, W2, dis, p);
    gather2_kernel<<<2048, 256, 0, stream>>>(p, adj, offs, dis, b2, batch, sums);
    fc_kernel<<<N_GRAPHS, 64, 0, stream>>>(sums, batch, Wfc, bfc, out);
}